// Round 1
// baseline (44097.058 us; speedup 1.0000x reference)
//
#include <hip/hip_runtime.h>
#include <hip/hip_cooperative_groups.h>

namespace cg = cooperative_groups;

#define T_  512
#define B_  64
#define F_  256
#define E_  512
// fused K for encoder = E_ (h) + F_ (x) = 768, tiled as 6 tiles of 128
// decoder K = F_ = 256, tiled as 2 tiles of 128

__device__ __forceinline__ float sigmoidf_(float x) {
    return 1.0f / (1.0f + __expf(-x));
}

__global__ __launch_bounds__(512)
void autoenc_kernel(const float* __restrict__ seq,
                    const float* __restrict__ WihF, const float* __restrict__ WhhF, const float* __restrict__ bF,
                    const float* __restrict__ WihB, const float* __restrict__ WhhB, const float* __restrict__ bB,
                    const float* __restrict__ dWih, const float* __restrict__ dWhh, const float* __restrict__ db,
                    float* __restrict__ out, float* __restrict__ ws)
{
    cg::grid_group grid = cg::this_grid();
    const int tid = threadIdx.x;
    const int bid = blockIdx.x;

    // ---- workspace layout (floats), all h states stored TRANSPOSED [dim][B] ----
    float* hTf  = ws;                          // [2][E_][B_] ping-pong
    float* hTb  = ws + 2 * E_ * B_;            // [2][E_][B_]
    float* hdT  = ws + 4 * E_ * B_;            // [2][F_][B_]
    float* xp0T = ws + 4 * E_ * B_ + 2 * F_ * B_; // [4F_][B_] incl. bias

    __shared__ float buf[128 * 65];    // [k][b] staging tile, padded
    __shared__ float preLDS[16 * 65];  // gate preactivations [row][b]
    __shared__ float cLDS[64 * 4];     // block-private cell state

    // ---- phase 0: zero-init all recurrent state (ws is poisoned 0xAA) ----
    {
        const int total = 4 * E_ * B_ + 2 * F_ * B_;
        for (int i = bid * 512 + tid; i < total; i += gridDim.x * 512) ws[i] = 0.0f;
    }
    for (int i = tid; i < 64 * 4; i += 512) cLDS[i] = 0.0f;
    __syncthreads();
    grid.sync();

    // ================= encoder: bidirectional LSTM =================
    {
        const int dir = bid >> 7;      // 0 = fwd (blocks 0..127), 1 = bwd
        const int blk = bid & 127;
        const int e0  = blk * 4;       // this block owns h dims [e0, e0+4)
        const float* Wih  = dir ? WihB : WihF;
        const float* Whh  = dir ? WhhB : WhhF;
        const float* bias = dir ? bB   : bF;
        float* hT = dir ? hTb : hTf;

        const int b  = tid & 63;
        const int rg = __builtin_amdgcn_readfirstlane(tid >> 6);   // wave id 0..7
        // block-local rows rr = 2*rg, 2*rg+1 ; rr = g*4 + j <-> global row g*E_ + e0 + j
        const int rr0 = 2 * rg, rr1 = 2 * rg + 1;
        const int grow0 = (rr0 >> 2) * E_ + e0 + (rr0 & 3);
        const int grow1 = (rr1 >> 2) * E_ + e0 + (rr1 & 3);

        for (int t = 0; t < T_; ++t) {
            const int p = t & 1, np = p ^ 1;
            const int t_eff = dir ? (T_ - 1 - t) : t;
            const float* hsrc = hT + p * E_ * B_;

            float acc0 = 0.0f, acc1 = 0.0f;
            for (int kt = 0; kt < 6; ++kt) {
                __syncthreads();   // previous tile fully consumed
                if (kt < 4) {
                    // stage h rows [kt*128, kt*128+128), layout already [k][b]
                    const float4* src4 = (const float4*)(hsrc + kt * 128 * B_);
                    #pragma unroll
                    for (int s = 0; s < 4; ++s) {
                        int idx = tid + s * 512;          // 0..2047
                        int row = idx >> 4, q = idx & 15; // 128 rows x 16 float4
                        float4 v = src4[row * 16 + q];
                        float* d = &buf[row * 65 + q * 4];
                        d[0] = v.x; d[1] = v.y; d[2] = v.z; d[3] = v.w;
                    }
                } else {
                    // stage x slice (transpose [b][i] -> [i][b])
                    const int i0 = (kt - 4) * 128;
                    const float4* src4 = (const float4*)(seq + (size_t)t_eff * B_ * F_);
                    #pragma unroll
                    for (int s = 0; s < 4; ++s) {
                        int idx = tid + s * 512;          // 64 b x 32 q
                        int bb = idx >> 5, q = idx & 31;
                        float4 v = src4[bb * (F_ / 4) + (i0 >> 2) + q];
                        buf[(q * 4 + 0) * 65 + bb] = v.x;
                        buf[(q * 4 + 1) * 65 + bb] = v.y;
                        buf[(q * 4 + 2) * 65 + bb] = v.z;
                        buf[(q * 4 + 3) * 65 + bb] = v.w;
                    }
                }
                __syncthreads();
                const float* w0;
                const float* w1;
                if (kt < 4) { w0 = Whh + (size_t)grow0 * E_ + kt * 128;
                              w1 = Whh + (size_t)grow1 * E_ + kt * 128; }
                else        { w0 = Wih + (size_t)grow0 * F_ + (kt - 4) * 128;
                              w1 = Wih + (size_t)grow1 * F_ + (kt - 4) * 128; }
                #pragma unroll 8
                for (int kk = 0; kk < 128; ++kk) {
                    float xv = buf[kk * 65 + b];
                    acc0 = fmaf(w0[kk], xv, acc0);
                    acc1 = fmaf(w1[kk], xv, acc1);
                }
            }
            preLDS[rr0 * 65 + b] = acc0;
            preLDS[rr1 * 65 + b] = acc1;
            __syncthreads();
            if (tid < 256) {
                const int bb = tid & 63, j = tid >> 6;   // j in [0,4)
                float gi = preLDS[(0 * 4 + j) * 65 + bb] + bias[0 * E_ + e0 + j];
                float gf = preLDS[(1 * 4 + j) * 65 + bb] + bias[1 * E_ + e0 + j];
                float gg = preLDS[(2 * 4 + j) * 65 + bb] + bias[2 * E_ + e0 + j];
                float go = preLDS[(3 * 4 + j) * 65 + bb] + bias[3 * E_ + e0 + j];
                float c = cLDS[j * 64 + bb];
                c = sigmoidf_(gf) * c + sigmoidf_(gi) * tanhf(gg);
                float h = sigmoidf_(go) * tanhf(c);
                cLDS[j * 64 + bb] = c;
                hT[np * E_ * B_ + (e0 + j) * B_ + bb] = h;   // coalesced [e][b]
            }
            grid.sync();
        }
    }
    // final encoder h is in ping 0 of hTf / hTb

    // ================= xp0 = x0 @ dec_Wih^T + dec_b (one-time) =================
    {
        if (tid < 256) {
            const int b  = tid & 63;
            const int r4 = __builtin_amdgcn_readfirstlane(tid >> 6);  // 0..3
            const int r  = bid * 4 + r4;                               // 0..1023
            const float* wr = dWih + (size_t)r * (2 * E_);
            float acc = db[r];
            for (int k = 0; k < E_; ++k)
                acc = fmaf(wr[k], hTf[k * B_ + b], acc);
            for (int k = 0; k < E_; ++k)
                acc = fmaf(wr[E_ + k], hTb[k * B_ + b], acc);
            xp0T[r * B_ + b] = acc;
        }
        grid.sync();
    }

    // ================= decoder: 512 steps, constant input xp0 =================
    {
        const int fb = bid;            // this block owns hidden dim fb (0..255)
        const int b  = tid & 63;
        const int r4 = __builtin_amdgcn_readfirstlane((tid >> 6) & 3);
        for (int i = tid; i < 64; i += 512) cLDS[i] = 0.0f;
        __syncthreads();

        for (int t = 0; t < T_; ++t) {
            const int p = t & 1, np = p ^ 1;
            const float* hsrc = hdT + p * F_ * B_;

            float acc = 0.0f;
            for (int kt = 0; kt < 2; ++kt) {
                __syncthreads();
                const float4* src4 = (const float4*)(hsrc + kt * 128 * B_);
                #pragma unroll
                for (int s = 0; s < 4; ++s) {
                    int idx = tid + s * 512;
                    int row = idx >> 4, q = idx & 15;
                    float4 v = src4[row * 16 + q];
                    float* d = &buf[row * 65 + q * 4];
                    d[0] = v.x; d[1] = v.y; d[2] = v.z; d[3] = v.w;
                }
                __syncthreads();
                if (tid < 256) {
                    const float* wr = dWhh + (size_t)(r4 * F_ + fb) * F_ + kt * 128;
                    #pragma unroll 8
                    for (int kk = 0; kk < 128; ++kk)
                        acc = fmaf(wr[kk], buf[kk * 65 + b], acc);
                }
            }
            if (tid < 256) preLDS[r4 * 65 + b] = acc;
            __syncthreads();
            if (tid < 64) {
                const int bb = tid;
                float gi = preLDS[0 * 65 + bb] + xp0T[(0 * F_ + fb) * B_ + bb];
                float gf = preLDS[1 * 65 + bb] + xp0T[(1 * F_ + fb) * B_ + bb];
                float gg = preLDS[2 * 65 + bb] + xp0T[(2 * F_ + fb) * B_ + bb];
                float go = preLDS[3 * 65 + bb] + xp0T[(3 * F_ + fb) * B_ + bb];
                float c = cLDS[bb];
                c = sigmoidf_(gf) * c + sigmoidf_(gi) * tanhf(gg);
                float h = sigmoidf_(go) * tanhf(c);
                cLDS[bb] = c;
                hdT[np * F_ * B_ + fb * B_ + bb] = h;                  // coalesced
                out[(size_t)t * B_ * F_ + (size_t)bb * F_ + fb] = h;   // preds[t,b,f]
            }
            grid.sync();
        }
    }
}

extern "C" void kernel_launch(void* const* d_in, const int* in_sizes, int n_in,
                              void* d_out, int out_size, void* d_ws, size_t ws_size,
                              hipStream_t stream) {
    const float* seq  = (const float*)d_in[0];
    const float* WihF = (const float*)d_in[1];
    const float* WhhF = (const float*)d_in[2];
    const float* bF   = (const float*)d_in[3];
    const float* WihB = (const float*)d_in[4];
    const float* WhhB = (const float*)d_in[5];
    const float* bB   = (const float*)d_in[6];
    const float* dWih = (const float*)d_in[7];
    const float* dWhh = (const float*)d_in[8];
    const float* db   = (const float*)d_in[9];
    float* out = (float*)d_out;
    float* ws  = (float*)d_ws;

    void* args[] = { &seq, &WihF, &WhhF, &bF, &WihB, &WhhB, &bB,
                     &dWih, &dWhh, &db, &out, &ws };
    hipLaunchCooperativeKernel((void*)autoenc_kernel, dim3(256), dim3(512),
                               args, 0, stream);
}

// Round 2
// 18330.125 us; speedup vs baseline: 2.4057x; 2.4057x over previous
//
#include <hip/hip_runtime.h>
#include <hip/hip_cooperative_groups.h>

namespace cg = cooperative_groups;

#define T_  512
#define B_  64
#define F_  256
#define E_  512
#define AGENT __HIP_MEMORY_SCOPE_AGENT

__device__ __forceinline__ float sigmoidf_(float x) {
    return 1.0f / (1.0f + __expf(-x));
}

// ---- agent-scope relaxed atomics: coherent at fabric, no fences, no L2 pollution ----
__device__ __forceinline__ float aload_f(const float* p) {
    return __hip_atomic_load(p, __ATOMIC_RELAXED, AGENT);
}
__device__ __forceinline__ float2 aload_f2(const float* p) {
    unsigned long long v = __hip_atomic_load((const unsigned long long*)p,
                                             __ATOMIC_RELAXED, AGENT);
    float2 r;
    r.x = __uint_as_float((unsigned)(v & 0xffffffffull));
    r.y = __uint_as_float((unsigned)(v >> 32));
    return r;
}
__device__ __forceinline__ void astore_f(float* p, float v) {
    __hip_atomic_store(p, v, __ATOMIC_RELAXED, AGENT);
}

// monotonic-counter barrier: no reset, no fences. __syncthreads drains vmcnt
// (compiler emits s_waitcnt vmcnt(0) before s_barrier) so all atomic h-stores
// are at the coherence point before tid0 signals.
__device__ __forceinline__ void gbar(unsigned* ctr, unsigned target, int tid) {
    __syncthreads();
    if (tid == 0) {
        __hip_atomic_fetch_add(ctr, 1u, __ATOMIC_RELAXED, AGENT);
        while (__hip_atomic_load(ctr, __ATOMIC_RELAXED, AGENT) < target) {}
    }
    __syncthreads();
}

__global__ __launch_bounds__(512)
void autoenc_kernel(const float* __restrict__ seq,
                    const float* __restrict__ WihF, const float* __restrict__ WhhF, const float* __restrict__ bF,
                    const float* __restrict__ WihB, const float* __restrict__ WhhB, const float* __restrict__ bB,
                    const float* __restrict__ dWih, const float* __restrict__ dWhh, const float* __restrict__ db,
                    float* __restrict__ out, float* __restrict__ ws)
{
    cg::grid_group grid = cg::this_grid();
    const int tid = threadIdx.x;
    const int bid = blockIdx.x;

    // ---- workspace (floats), h states TRANSPOSED [dim][B]; atomics-only regions ----
    float* hTf  = ws;                          // [2][E][B] ping-pong (atomic only)
    float* hTb  = ws + 2 * E_ * B_;            // [2][E][B] (atomic only)
    float* hdT  = ws + 4 * E_ * B_;            // [2][F][B] (atomic only)
    float* xp0T = ws + 4 * E_ * B_ + 2 * F_ * B_;              // [4F][B] write-once atomic, then cached reads
    unsigned* ctrs = (unsigned*)(ws + 4 * E_ * B_ + 2 * F_ * B_ + 4 * F_ * B_);
    unsigned* ctrF = ctrs + 0;     // encoder fwd barrier (128 blocks)
    unsigned* ctrB = ctrs + 64;    // encoder bwd barrier (128 blocks)
    unsigned* ctrD = ctrs + 128;   // xp0 (256) + decoder (64) barrier

    __shared__ float buf[128 * 65];     // staged [k][b] tile
    __shared__ float part[8 * 16 * 65]; // per-wave partial sums
    __shared__ float pre[16 * 65];      // reduced gate preactivations
    __shared__ float cLDS[4 * 64];      // block-private cell state

    // ---- init: zero h states + barrier counters (atomic stores only — these
    // lines must never become dirty in any L2) ----
    {
        const int totalf = 4 * E_ * B_ + 2 * F_ * B_;
        for (int i = bid * 512 + tid; i < totalf; i += 256 * 512)
            astore_f(ws + i, 0.0f);
        if (bid == 0 && tid < 192)
            __hip_atomic_store(ctrs + tid, 0u, __ATOMIC_RELAXED, AGENT);
    }
    grid.sync();   // one-time full fence; weights warm into L2 after this

    // ================= encoder: bidirectional LSTM =================
    {
        const int dir = bid >> 7;          // 0 fwd / 1 bwd
        const int blk = bid & 127;
        const int e0  = blk * 4;           // owns h dims [e0, e0+4)
        const float* Wih  = dir ? WihB : WihF;
        const float* Whh  = dir ? WhhB : WhhF;
        const float* bias = dir ? bB   : bF;
        float* hT = dir ? hTb : hTf;
        unsigned* ctr = dir ? ctrB : ctrF;

        const int b = tid & 63;
        const int g = __builtin_amdgcn_readfirstlane(tid >> 6);  // wave 0..7

        for (int i = tid; i < 4 * 64; i += 512) cLDS[i] = 0.0f;

        float acc[16];

        for (int t = 0; t < T_; ++t) {
            const int p = t & 1, np = p ^ 1;
            const int t_eff = dir ? (T_ - 1 - t) : t;
            const float* hsrc = hT + p * E_ * B_;

            #pragma unroll
            for (int r = 0; r < 16; ++r) acc[r] = 0.0f;

            for (int kt = 0; kt < 6; ++kt) {
                __syncthreads();
                if (kt < 4) {
                    // stage h rows [kt*128, kt*128+128) via coherent u64 loads
                    const float* src = hsrc + kt * 128 * B_;
                    #pragma unroll
                    for (int s = 0; s < 8; ++s) {
                        int u = tid + s * 512;            // 0..4095
                        int row = u >> 5, pr = u & 31;    // 128 rows x 32 pairs
                        float2 v = aload_f2(src + row * B_ + pr * 2);
                        buf[row * 65 + pr * 2 + 0] = v.x;
                        buf[row * 65 + pr * 2 + 1] = v.y;
                    }
                } else {
                    // stage x slice (normal cached loads; transpose [b][i]->[i][b])
                    const int i0 = (kt - 4) * 128;
                    const float4* src4 = (const float4*)(seq + (size_t)t_eff * B_ * F_);
                    #pragma unroll
                    for (int s = 0; s < 4; ++s) {
                        int idx = tid + s * 512;
                        int bb = idx >> 5, q = idx & 31;
                        float4 v = src4[bb * (F_ / 4) + (i0 >> 2) + q];
                        buf[(q * 4 + 0) * 65 + bb] = v.x;
                        buf[(q * 4 + 1) * 65 + bb] = v.y;
                        buf[(q * 4 + 2) * 65 + bb] = v.z;
                        buf[(q * 4 + 3) * 65 + bb] = v.w;
                    }
                }
                __syncthreads();
                // K-split: wave g handles k-slice [g*16, g*16+16) of this tile,
                // all 16 rows — each LDS value reused 16x from register.
                const int kbase = kt * 128 + g * 16;
                const float* W = (kt < 4) ? Whh : Wih;
                const int K    = (kt < 4) ? E_ : F_;
                const int koff = (kt < 4) ? kbase : (kbase - E_);
                #pragma unroll
                for (int kk = 0; kk < 16; ++kk) {
                    float xv = buf[(g * 16 + kk) * 65 + b];
                    #pragma unroll
                    for (int r = 0; r < 16; ++r) {
                        const int grow = (r >> 2) * E_ + e0 + (r & 3);  // gate*E + e0 + j
                        acc[r] = fmaf(W[(size_t)grow * K + koff + kk], xv, acc[r]);
                    }
                }
            }
            // wave partials -> LDS, reduce 8-way
            #pragma unroll
            for (int r = 0; r < 16; ++r) part[(g * 16 + r) * 65 + b] = acc[r];
            __syncthreads();
            {
                const int r0 = tid >> 6;   // 0..7, b = tid&63
                #pragma unroll
                for (int h2 = 0; h2 < 2; ++h2) {
                    const int r = r0 + h2 * 8;
                    float sum = 0.0f;
                    #pragma unroll
                    for (int gg = 0; gg < 8; ++gg) sum += part[(gg * 16 + r) * 65 + b];
                    pre[r * 65 + b] = sum;
                }
            }
            __syncthreads();
            if (tid < 256) {
                const int bb = tid & 63, j = tid >> 6;
                float gI = pre[(0 * 4 + j) * 65 + bb] + bias[0 * E_ + e0 + j];
                float gF = pre[(1 * 4 + j) * 65 + bb] + bias[1 * E_ + e0 + j];
                float gG = pre[(2 * 4 + j) * 65 + bb] + bias[2 * E_ + e0 + j];
                float gO = pre[(3 * 4 + j) * 65 + bb] + bias[3 * E_ + e0 + j];
                float c = cLDS[j * 64 + bb];
                c = sigmoidf_(gF) * c + sigmoidf_(gI) * tanhf(gG);
                float h = sigmoidf_(gO) * tanhf(c);
                cLDS[j * 64 + bb] = c;
                astore_f(&hT[np * E_ * B_ + (e0 + j) * B_ + bb], h);
            }
            gbar(ctr, (unsigned)(128 * (t + 1)), tid);
        }
        // wait for the other direction to finish all 512 steps
        __syncthreads();
        if (tid == 0) {
            unsigned* octr = dir ? ctrF : ctrB;
            while (__hip_atomic_load(octr, __ATOMIC_RELAXED, AGENT) < 128u * T_) {}
        }
        __syncthreads();
    }

    // ================= xp0 = [h_f | h_b] @ dec_Wih^T + dec_b (one-time) =================
    {
        const int b  = tid & 63;
        const int r4 = (tid >> 6) & 3;
        const int r  = bid * 4 + r4;                 // 0..1023
        const float* wr = dWih + (size_t)r * (2 * E_);
        float accv = db[r];
        // final encoder h is ping 0 of hTf / hTb
        for (int ch = 0; ch < 8; ++ch) {
            const float* hsrc = (ch < 4 ? hTf : hTb) + (ch & 3) * 128 * B_;
            __syncthreads();
            #pragma unroll
            for (int s = 0; s < 8; ++s) {
                int u = tid + s * 512;
                int row = u >> 5, pr = u & 31;
                float2 v = aload_f2(hsrc + row * B_ + pr * 2);
                buf[row * 65 + pr * 2 + 0] = v.x;
                buf[row * 65 + pr * 2 + 1] = v.y;
            }
            __syncthreads();
            if (tid < 256) {
                const float* w = wr + ch * 128;
                #pragma unroll 8
                for (int kk = 0; kk < 128; ++kk)
                    accv = fmaf(w[kk], buf[kk * 65 + b], accv);
            }
        }
        if (tid < 256) astore_f(&xp0T[r * B_ + b], accv);
        gbar(ctrD, 256u, tid);
    }

    // ================= decoder: 64 blocks x 4 f-dims, 512 steps =================
    if (bid >= 64) return;   // no further barriers involve these blocks
    {
        const int fb0 = bid * 4;                 // owns f dims [fb0, fb0+4)
        const int b = tid & 63;
        const int g = __builtin_amdgcn_readfirstlane(tid >> 6);

        for (int i = tid; i < 4 * 64; i += 512) cLDS[i] = 0.0f;

        float acc[16];

        for (int t = 0; t < T_; ++t) {
            const int p = t & 1, np = p ^ 1;
            const float* hsrc = hdT + p * F_ * B_;

            #pragma unroll
            for (int r = 0; r < 16; ++r) acc[r] = 0.0f;

            for (int kt = 0; kt < 2; ++kt) {
                __syncthreads();
                const float* src = hsrc + kt * 128 * B_;
                #pragma unroll
                for (int s = 0; s < 8; ++s) {
                    int u = tid + s * 512;
                    int row = u >> 5, pr = u & 31;
                    float2 v = aload_f2(src + row * B_ + pr * 2);
                    buf[row * 65 + pr * 2 + 0] = v.x;
                    buf[row * 65 + pr * 2 + 1] = v.y;
                }
                __syncthreads();
                const int koff = kt * 128 + g * 16;
                #pragma unroll
                for (int kk = 0; kk < 16; ++kk) {
                    float xv = buf[(g * 16 + kk) * 65 + b];
                    #pragma unroll
                    for (int r = 0; r < 16; ++r) {
                        const int grow = (r >> 2) * F_ + fb0 + (r & 3);  // gate*F + fb0 + j
                        acc[r] = fmaf(dWhh[(size_t)grow * F_ + koff + kk], xv, acc[r]);
                    }
                }
            }
            #pragma unroll
            for (int r = 0; r < 16; ++r) part[(g * 16 + r) * 65 + b] = acc[r];
            __syncthreads();
            {
                const int r0 = tid >> 6;
                #pragma unroll
                for (int h2 = 0; h2 < 2; ++h2) {
                    const int r = r0 + h2 * 8;
                    float sum = 0.0f;
                    #pragma unroll
                    for (int gg = 0; gg < 8; ++gg) sum += part[(gg * 16 + r) * 65 + b];
                    pre[r * 65 + b] = sum;
                }
            }
            __syncthreads();
            if (tid < 256) {
                const int bb = tid & 63, j = tid >> 6;
                float gI = pre[(0 * 4 + j) * 65 + bb] + xp0T[(0 * F_ + fb0 + j) * B_ + bb];
                float gF = pre[(1 * 4 + j) * 65 + bb] + xp0T[(1 * F_ + fb0 + j) * B_ + bb];
                float gG = pre[(2 * 4 + j) * 65 + bb] + xp0T[(2 * F_ + fb0 + j) * B_ + bb];
                float gO = pre[(3 * 4 + j) * 65 + bb] + xp0T[(3 * F_ + fb0 + j) * B_ + bb];
                float c = cLDS[j * 64 + bb];
                c = sigmoidf_(gF) * c + sigmoidf_(gI) * tanhf(gG);
                float h = sigmoidf_(gO) * tanhf(c);
                cLDS[j * 64 + bb] = c;
                astore_f(&hdT[np * F_ * B_ + (fb0 + j) * B_ + bb], h);
                out[(size_t)t * B_ * F_ + (size_t)bb * F_ + fb0 + j] = h;  // 16B/bb chunks
            }
            gbar(ctrD, 256u + 64u * (t + 1), tid);
        }
    }
}

extern "C" void kernel_launch(void* const* d_in, const int* in_sizes, int n_in,
                              void* d_out, int out_size, void* d_ws, size_t ws_size,
                              hipStream_t stream) {
    const float* seq  = (const float*)d_in[0];
    const float* WihF = (const float*)d_in[1];
    const float* WhhF = (const float*)d_in[2];
    const float* bF   = (const float*)d_in[3];
    const float* WihB = (const float*)d_in[4];
    const float* WhhB = (const float*)d_in[5];
    const float* bB   = (const float*)d_in[6];
    const float* dWih = (const float*)d_in[7];
    const float* dWhh = (const float*)d_in[8];
    const float* db   = (const float*)d_in[9];
    float* out = (float*)d_out;
    float* ws  = (float*)d_ws;

    void* args[] = { &seq, &WihF, &WhhF, &bF, &WihB, &WhhB, &bB,
                     &dWih, &dWhh, &db, &out, &ws };
    hipLaunchCooperativeKernel((void*)autoenc_kernel, dim3(256), dim3(512),
                               args, 0, stream);
}

// Round 3
// 14801.384 us; speedup vs baseline: 2.9793x; 1.2384x over previous
//
#include <hip/hip_runtime.h>
#include <hip/hip_cooperative_groups.h>

namespace cg = cooperative_groups;

#define T_  512
#define B_  64
#define F_  256
#define E_  512
#define AGENT __HIP_MEMORY_SCOPE_AGENT

__device__ __forceinline__ float sigmoidf_(float x) {
    return 1.0f / (1.0f + __expf(-x));
}

// ---- agent-scope relaxed atomics: coherent at fabric, no fences ----
__device__ __forceinline__ float aload_f(const float* p) {
    return __hip_atomic_load(p, __ATOMIC_RELAXED, AGENT);
}
__device__ __forceinline__ float2 aload_f2(const float* p) {
    unsigned long long v = __hip_atomic_load((const unsigned long long*)p,
                                             __ATOMIC_RELAXED, AGENT);
    float2 r;
    r.x = __uint_as_float((unsigned)(v & 0xffffffffull));
    r.y = __uint_as_float((unsigned)(v >> 32));
    return r;
}
__device__ __forceinline__ void astore_f(float* p, float v) {
    __hip_atomic_store(p, v, __ATOMIC_RELAXED, AGENT);
}

// ---- store-slot barriers: plain-store arrival (no RMW contention),
// wave-0 polls all slots with packed u64 loads. Monotonic targets, no reset.
// __syncthreads before arrival drains vmcnt so h-stores are at the coherence
// point before the slot store issues.
__device__ __forceinline__ void bar128(unsigned* slots, unsigned* myslot,
                                       unsigned target, int tid) {
    __syncthreads();
    if (tid == 0) __hip_atomic_store(myslot, target, __ATOMIC_RELAXED, AGENT);
    if (tid < 64) {
        const unsigned long long* p = (const unsigned long long*)slots;
        bool ok;
        do {
            unsigned long long v = __hip_atomic_load(p + tid, __ATOMIC_RELAXED, AGENT);
            ok = ((unsigned)v >= target) && ((unsigned)(v >> 32) >= target);
        } while (!__all(ok));
    }
    __syncthreads();
}

__device__ __forceinline__ void wait128(const unsigned* slots, unsigned target, int tid) {
    if (tid < 64) {
        const unsigned long long* p = (const unsigned long long*)slots;
        bool ok;
        do {
            unsigned long long v = __hip_atomic_load(p + tid, __ATOMIC_RELAXED, AGENT);
            ok = ((unsigned)v >= target) && ((unsigned)(v >> 32) >= target);
        } while (!__all(ok));
    }
    __syncthreads();
}

__device__ __forceinline__ void bar64(unsigned* slots, unsigned* myslot,
                                      unsigned target, int tid) {
    __syncthreads();
    if (tid == 0) __hip_atomic_store(myslot, target, __ATOMIC_RELAXED, AGENT);
    if (tid < 64) {
        bool ok;
        do {
            unsigned v = __hip_atomic_load(slots + tid, __ATOMIC_RELAXED, AGENT);
            ok = (v >= target);
        } while (!__all(ok));
    }
    __syncthreads();
}

__global__ __launch_bounds__(512)
void autoenc_kernel(const float* __restrict__ seq,
                    const float* __restrict__ WihF, const float* __restrict__ WhhF, const float* __restrict__ bF,
                    const float* __restrict__ WihB, const float* __restrict__ WhhB, const float* __restrict__ bB,
                    const float* __restrict__ dWih, const float* __restrict__ dWhh, const float* __restrict__ db,
                    float* __restrict__ out, float* __restrict__ ws)
{
    cg::grid_group grid = cg::this_grid();
    const int tid = threadIdx.x;
    const int bid = blockIdx.x;

    // ---- workspace layout (floats); h states TRANSPOSED [dim][B] ----
    float* hTf  = ws;                      // [2][E][B]  = 65536
    float* hTb  = ws + 65536;              // [2][E][B]  = 65536
    float* hdT  = ws + 131072;             // [2][F][B]  = 32768
    float* xp0T = ws + 163840;             // [4F][B]    = 65536
    unsigned* slotsF = (unsigned*)(ws + 229376);   // [128]
    unsigned* slotsB = slotsF + 128;               // [128]
    unsigned* slotsX = slotsB + 128;               // [256]
    unsigned* slotsD = slotsX + 256;               // [64]

    __shared__ float buf[128 * 65];     // staged [k][b] tile
    __shared__ float part[8 * 16 * 65]; // per-wave partial sums
    __shared__ float pre[16 * 65];      // reduced gate preactivations
    __shared__ float cLDS[4 * 64];      // block-private cell state
    __shared__ float xpLDS[16 * 64];    // decoder xp0 slice

    // ---- init: zero recurrent states + barrier slots (sc1 stores only) ----
    {
        for (int i = bid * 512 + tid; i < 163840; i += 256 * 512)
            astore_f(ws + i, 0.0f);
        if (bid == 0)
            for (int i = tid; i < 576; i += 512)
                __hip_atomic_store(slotsF + i, 0u, __ATOMIC_RELAXED, AGENT);
    }
    grid.sync();   // one-time full fence; weights stay L2-warm afterwards

    // ================= encoder: bidirectional LSTM =================
    {
        const int dir = bid >> 7;          // 0 fwd / 1 bwd
        const int blk = bid & 127;
        const int e0  = blk * 4;           // owns h dims [e0, e0+4)
        const float* Wih  = dir ? WihB : WihF;
        const float* Whh  = dir ? WhhB : WhhF;
        const float* bias = dir ? bB   : bF;
        float* hT = dir ? hTb : hTf;
        unsigned* slots  = dir ? slotsB : slotsF;
        unsigned* myslot = slots + blk;

        const int b = tid & 63;
        const int g = __builtin_amdgcn_readfirstlane(tid >> 6);  // wave 0..7

        for (int i = tid; i < 4 * 64; i += 512) cLDS[i] = 0.0f;

        // hoisted per-thread bias (epilogue lanes only)
        float bGi = 0, bGf = 0, bGg = 0, bGo = 0;
        if (tid < 256) {
            const int j = tid >> 6;
            bGi = bias[0 * E_ + e0 + j];
            bGf = bias[1 * E_ + e0 + j];
            bGg = bias[2 * E_ + e0 + j];
            bGo = bias[3 * E_ + e0 + j];
        }
        __syncthreads();

        float acc[16];
        float2 pf[8];
        float4 px[4];

        for (int t = 0; t < T_; ++t) {
            const int p = t & 1, np = p ^ 1;
            const int t_eff = dir ? (T_ - 1 - t) : t;
            const float* hsrc = hT + p * E_ * B_;
            const float4* xs4 = (const float4*)(seq + (size_t)t_eff * B_ * F_);

            #pragma unroll
            for (int r = 0; r < 16; ++r) acc[r] = 0.0f;

            // prefetch tile 0 (h rows 0..127)
            #pragma unroll
            for (int s = 0; s < 8; ++s) {
                int u = tid + s * 512, row = u >> 5, pr = u & 31;
                pf[s] = aload_f2(hsrc + row * B_ + pr * 2);
            }

            for (int kt = 0; kt < 6; ++kt) {
                __syncthreads();   // prev tile consumed
                if (kt < 4) {
                    #pragma unroll
                    for (int s = 0; s < 8; ++s) {
                        int u = tid + s * 512, row = u >> 5, pr = u & 31;
                        buf[row * 65 + pr * 2 + 0] = pf[s].x;
                        buf[row * 65 + pr * 2 + 1] = pf[s].y;
                    }
                } else {
                    #pragma unroll
                    for (int s = 0; s < 4; ++s) {
                        int idx = tid + s * 512, bb = idx >> 5, q = idx & 31;
                        buf[(q * 4 + 0) * 65 + bb] = px[s].x;
                        buf[(q * 4 + 1) * 65 + bb] = px[s].y;
                        buf[(q * 4 + 2) * 65 + bb] = px[s].z;
                        buf[(q * 4 + 3) * 65 + bb] = px[s].w;
                    }
                }
                __syncthreads();   // tile ready
                // prefetch next tile (overlaps compute below)
                if (kt < 3) {
                    const float* src = hsrc + (kt + 1) * 128 * B_;
                    #pragma unroll
                    for (int s = 0; s < 8; ++s) {
                        int u = tid + s * 512, row = u >> 5, pr = u & 31;
                        pf[s] = aload_f2(src + row * B_ + pr * 2);
                    }
                } else if (kt < 5) {
                    const int xi = kt - 3;   // 0 at kt==3, 1 at kt==4
                    #pragma unroll
                    for (int s = 0; s < 4; ++s) {
                        int idx = tid + s * 512, bb = idx >> 5, q = idx & 31;
                        px[s] = xs4[bb * 64 + xi * 32 + q];
                    }
                }
                // compute tile kt: wave g owns k-slice [g*16, g*16+16)
                const float* W = (kt < 4) ? Whh : Wih;
                const int K    = (kt < 4) ? E_ : F_;
                const int koff = (kt < 4) ? (kt * 128 + g * 16)
                                          : ((kt - 4) * 128 + g * 16);
                #pragma unroll
                for (int kk = 0; kk < 16; ++kk) {
                    float xv = buf[(g * 16 + kk) * 65 + b];
                    #pragma unroll
                    for (int r = 0; r < 16; ++r) {
                        const int grow = (r >> 2) * E_ + e0 + (r & 3);
                        acc[r] = fmaf(W[(size_t)grow * K + koff + kk], xv, acc[r]);
                    }
                }
            }
            // wave partials -> LDS, 8-way reduce
            #pragma unroll
            for (int r = 0; r < 16; ++r) part[(g * 16 + r) * 65 + b] = acc[r];
            __syncthreads();
            {
                const int r0 = tid >> 6;
                #pragma unroll
                for (int h2 = 0; h2 < 2; ++h2) {
                    const int r = r0 + h2 * 8;
                    float sum = 0.0f;
                    #pragma unroll
                    for (int gg = 0; gg < 8; ++gg) sum += part[(gg * 16 + r) * 65 + b];
                    pre[r * 65 + b] = sum;
                }
            }
            __syncthreads();
            if (tid < 256) {
                const int bb = tid & 63, j = tid >> 6;
                float gI = pre[(0 * 4 + j) * 65 + bb] + bGi;
                float gF = pre[(1 * 4 + j) * 65 + bb] + bGf;
                float gG = pre[(2 * 4 + j) * 65 + bb] + bGg;
                float gO = pre[(3 * 4 + j) * 65 + bb] + bGo;
                float c = cLDS[j * 64 + bb];
                c = sigmoidf_(gF) * c + sigmoidf_(gI) * tanhf(gG);
                float h = sigmoidf_(gO) * tanhf(c);
                cLDS[j * 64 + bb] = c;
                astore_f(&hT[np * E_ * B_ + (e0 + j) * B_ + bb], h);
            }
            bar128(slots, myslot, (unsigned)(t + 1), tid);
        }
        // wait for the other direction
        wait128(dir ? slotsF : slotsB, (unsigned)T_, tid);
    }

    // ================= xp0 = [h_f | h_b] @ dec_Wih^T + dec_b (one-time) =================
    {
        const int b  = tid & 63;
        const int r4 = (tid >> 6) & 3;
        const int r  = bid * 4 + r4;                 // 0..1023
        const float* wr = dWih + (size_t)r * (2 * E_);
        float accv = db[r];
        for (int ch = 0; ch < 8; ++ch) {
            const float* hsrc = (ch < 4 ? hTf : hTb) + (ch & 3) * 128 * B_;
            __syncthreads();
            #pragma unroll
            for (int s = 0; s < 8; ++s) {
                int u = tid + s * 512, row = u >> 5, pr = u & 31;
                float2 v = aload_f2(hsrc + row * B_ + pr * 2);
                buf[row * 65 + pr * 2 + 0] = v.x;
                buf[row * 65 + pr * 2 + 1] = v.y;
            }
            __syncthreads();
            if (tid < 256) {
                const float* w = wr + ch * 128;
                #pragma unroll 8
                for (int kk = 0; kk < 128; ++kk)
                    accv = fmaf(w[kk], buf[kk * 65 + b], accv);
            }
        }
        if (tid < 256) astore_f(&xp0T[r * B_ + b], accv);
        // arrive on slotsX; only decoder blocks poll
        __syncthreads();
        if (tid == 0) __hip_atomic_store(slotsX + bid, 1u, __ATOMIC_RELAXED, AGENT);
        if (bid >= 64) return;
        if (tid < 64) {
            const unsigned long long* pp = (const unsigned long long*)slotsX;
            bool ok;
            do {
                unsigned long long v0 = __hip_atomic_load(pp + 2 * tid,     __ATOMIC_RELAXED, AGENT);
                unsigned long long v1 = __hip_atomic_load(pp + 2 * tid + 1, __ATOMIC_RELAXED, AGENT);
                ok = ((unsigned)v0 != 0u) && ((unsigned)(v0 >> 32) != 0u) &&
                     ((unsigned)v1 != 0u) && ((unsigned)(v1 >> 32) != 0u);
            } while (!__all(ok));
        }
        __syncthreads();
    }

    // ================= decoder: 64 blocks x 4 f-dims, 512 steps =================
    {
        const int fb0 = bid * 4;                 // owns f dims [fb0, fb0+4)
        const int b = tid & 63;
        const int g = __builtin_amdgcn_readfirstlane(tid >> 6);

        for (int i = tid; i < 4 * 64; i += 512) cLDS[i] = 0.0f;
        // xp0 slice -> LDS (one-time)
        #pragma unroll
        for (int s = 0; s < 2; ++s) {
            int u = tid + s * 512;          // 0..1023
            int r16 = u >> 6, bb = u & 63;  // r16 = g*4 + j
            xpLDS[r16 * 64 + bb] =
                aload_f(&xp0T[((r16 >> 2) * F_ + fb0 + (r16 & 3)) * B_ + bb]);
        }
        __syncthreads();

        float acc[16];
        float2 pf[8];

        for (int t = 0; t < T_; ++t) {
            const int p = t & 1, np = p ^ 1;
            const float* hsrc = hdT + p * F_ * B_;

            #pragma unroll
            for (int r = 0; r < 16; ++r) acc[r] = 0.0f;

            // prefetch tile 0
            #pragma unroll
            for (int s = 0; s < 8; ++s) {
                int u = tid + s * 512, row = u >> 5, pr = u & 31;
                pf[s] = aload_f2(hsrc + row * B_ + pr * 2);
            }

            for (int kt = 0; kt < 2; ++kt) {
                __syncthreads();
                #pragma unroll
                for (int s = 0; s < 8; ++s) {
                    int u = tid + s * 512, row = u >> 5, pr = u & 31;
                    buf[row * 65 + pr * 2 + 0] = pf[s].x;
                    buf[row * 65 + pr * 2 + 1] = pf[s].y;
                }
                __syncthreads();
                if (kt == 0) {
                    const float* src = hsrc + 128 * B_;
                    #pragma unroll
                    for (int s = 0; s < 8; ++s) {
                        int u = tid + s * 512, row = u >> 5, pr = u & 31;
                        pf[s] = aload_f2(src + row * B_ + pr * 2);
                    }
                }
                const int koff = kt * 128 + g * 16;
                #pragma unroll
                for (int kk = 0; kk < 16; ++kk) {
                    float xv = buf[(g * 16 + kk) * 65 + b];
                    #pragma unroll
                    for (int r = 0; r < 16; ++r) {
                        const int grow = (r >> 2) * F_ + fb0 + (r & 3);
                        acc[r] = fmaf(dWhh[(size_t)grow * F_ + koff + kk], xv, acc[r]);
                    }
                }
            }
            #pragma unroll
            for (int r = 0; r < 16; ++r) part[(g * 16 + r) * 65 + b] = acc[r];
            __syncthreads();
            {
                const int r0 = tid >> 6;
                #pragma unroll
                for (int h2 = 0; h2 < 2; ++h2) {
                    const int r = r0 + h2 * 8;
                    float sum = 0.0f;
                    #pragma unroll
                    for (int gg = 0; gg < 8; ++gg) sum += part[(gg * 16 + r) * 65 + b];
                    pre[r * 65 + b] = sum;
                }
            }
            __syncthreads();
            if (tid < 256) {
                const int bb = tid & 63, j = tid >> 6;
                float gI = pre[(0 * 4 + j) * 65 + bb] + xpLDS[(0 * 4 + j) * 64 + bb];
                float gF = pre[(1 * 4 + j) * 65 + bb] + xpLDS[(1 * 4 + j) * 64 + bb];
                float gG = pre[(2 * 4 + j) * 65 + bb] + xpLDS[(2 * 4 + j) * 64 + bb];
                float gO = pre[(3 * 4 + j) * 65 + bb] + xpLDS[(3 * 4 + j) * 64 + bb];
                float c = cLDS[j * 64 + bb];
                c = sigmoidf_(gF) * c + sigmoidf_(gI) * tanhf(gG);
                float h = sigmoidf_(gO) * tanhf(c);
                cLDS[j * 64 + bb] = c;
                astore_f(&hdT[np * F_ * B_ + (fb0 + j) * B_ + bb], h);
                out[(size_t)t * B_ * F_ + (size_t)bb * F_ + fb0 + j] = h;
            }
            if (t + 1 < T_) bar64(slotsD, slotsD + bid, (unsigned)(t + 1), tid);
        }
    }
}

extern "C" void kernel_launch(void* const* d_in, const int* in_sizes, int n_in,
                              void* d_out, int out_size, void* d_ws, size_t ws_size,
                              hipStream_t stream) {
    const float* seq  = (const float*)d_in[0];
    const float* WihF = (const float*)d_in[1];
    const float* WhhF = (const float*)d_in[2];
    const float* bF   = (const float*)d_in[3];
    const float* WihB = (const float*)d_in[4];
    const float* WhhB = (const float*)d_in[5];
    const float* bB   = (const float*)d_in[6];
    const float* dWih = (const float*)d_in[7];
    const float* dWhh = (const float*)d_in[8];
    const float* db   = (const float*)d_in[9];
    float* out = (float*)d_out;
    float* ws  = (float*)d_ws;

    void* args[] = { &seq, &WihF, &WhhF, &bF, &WihB, &WhhB, &bB,
                     &dWih, &dWhh, &db, &out, &ws };
    hipLaunchCooperativeKernel((void*)autoenc_kernel, dim3(256), dim3(512),
                               args, 0, stream);
}

// Round 4
// 11311.589 us; speedup vs baseline: 3.8984x; 1.3085x over previous
//
#include <hip/hip_runtime.h>
#include <hip/hip_cooperative_groups.h>

namespace cg = cooperative_groups;

#define T_  512
#define B_  64
#define F_  256
#define E_  512
#define AGENT __HIP_MEMORY_SCOPE_AGENT

// ---- ws layout (bytes). Write-once rings: address of h[t] is unique per step,
// so producers sc1-store (bypass L2 -> L3) and consumers use NORMAL cached
// loads: no L2 line can be stale (never touched pre-write), and the per-XCD L2
// serves 15 of 16 blocks -> 16x less fabric traffic than sc1 broadcast.
#define OFF_HF   0ull                          // [T+1][E][B] bf16 = 33,619,968
#define OFF_HB   33619968ull                   // [T+1][E][B] bf16
#define OFF_HD   67239936ull                   // [T+1][F][B] bf16 = 16,809,984
#define OFF_XP   84049920ull                   // [4F][B] f32 = 262,144
#define OFF_SL   84312064ull                   // slots

__device__ __forceinline__ float sigmoidf_(float x) {
    return 1.0f / (1.0f + __expf(-x));
}
__device__ __forceinline__ unsigned short f2bf(float f) {   // RNE
    unsigned u = __float_as_uint(f);
    u += 0x7fffu + ((u >> 16) & 1u);
    return (unsigned short)(u >> 16);
}
__device__ __forceinline__ float bfbits2f(unsigned us) {
    return __uint_as_float(us << 16);
}
__device__ __forceinline__ void astore_u32(unsigned* p, unsigned v) {
    __hip_atomic_store(p, v, __ATOMIC_RELAXED, AGENT);
}
__device__ __forceinline__ unsigned long long aload_u64(const unsigned long long* p) {
    return __hip_atomic_load(p, __ATOMIC_RELAXED, AGENT);
}
__device__ __forceinline__ unsigned aload_u32(const unsigned* p) {
    return __hip_atomic_load(p, __ATOMIC_RELAXED, AGENT);
}
__device__ __forceinline__ void astore_us(unsigned short* p, unsigned short v) {
    __hip_atomic_store(p, v, __ATOMIC_RELAXED, AGENT);
}
__device__ __forceinline__ void astore_f(float* p, float v) {
    __hip_atomic_store(p, v, __ATOMIC_RELAXED, AGENT);
}

__global__ __launch_bounds__(512)
void autoenc_kernel(const float* __restrict__ seq,
                    const float* __restrict__ WihF, const float* __restrict__ WhhF, const float* __restrict__ bF,
                    const float* __restrict__ WihB, const float* __restrict__ WhhB, const float* __restrict__ bB,
                    const float* __restrict__ dWih, const float* __restrict__ dWhh, const float* __restrict__ db,
                    float* __restrict__ out, char* __restrict__ ws)
{
    cg::grid_group grid = cg::this_grid();
    const int tid = threadIdx.x;
    const int bid = blockIdx.x;

    unsigned short* hfR = (unsigned short*)(ws + OFF_HF);   // ring, stride E*B
    unsigned short* hbR = (unsigned short*)(ws + OFF_HB);
    unsigned short* hdR = (unsigned short*)(ws + OFF_HD);   // ring, stride F*B
    float*          xp0T = (float*)(ws + OFF_XP);
    unsigned* slotsF = (unsigned*)(ws + OFF_SL);            // [128]
    unsigned* slotsB = slotsF + 128;                        // [128]
    unsigned* slotsX = slotsB + 128;                        // [256]
    unsigned* slotsD = slotsX + 256;                        // [64]

    __shared__ float buf[128 * 65];     // staged [k][b] f32 tile
    __shared__ float part[8 * 16 * 65]; // per-wave partial sums
    __shared__ float pre[16 * 65];      // reduced gate preactivations
    __shared__ float cLDS[4 * 64];      // block-private cell state
    __shared__ float xpLDS[16 * 64];    // decoder xp0 slice

    // ---- init: zero ring[0] slabs + all slots, via sc1 (bypass L2) ----
    {
        unsigned* hf0 = (unsigned*)hfR;            // 16384 u32
        unsigned* hb0 = (unsigned*)hbR;            // 16384 u32
        unsigned* hd0 = (unsigned*)hdR;            // 8192 u32
        for (int i = bid * 512 + tid; i < 16384; i += 256 * 512) { astore_u32(hf0 + i, 0u); astore_u32(hb0 + i, 0u); }
        for (int i = bid * 512 + tid; i < 8192;  i += 256 * 512) astore_u32(hd0 + i, 0u);
        if (bid == 0) for (int i = tid; i < 576; i += 512) astore_u32(slotsF + i, 0u);
    }
    grid.sync();   // one-time device fence: L2s invalidated, ring[0]/slots visible

    // ================= encoder: bidirectional LSTM =================
    {
        const int dir = bid >> 7;          // 0 fwd / 1 bwd
        const int blk = bid & 127;
        const int e0  = blk * 4;           // owns h dims [e0, e0+4)
        const float* Wih  = dir ? WihB : WihF;
        const float* Whh  = dir ? WhhB : WhhF;
        const float* bias = dir ? bB   : bF;
        unsigned short* ring = dir ? hbR : hfR;
        unsigned* slots  = dir ? slotsB : slotsF;
        unsigned* myslot = slots + blk;

        const int b = tid & 63;
        const int g = __builtin_amdgcn_readfirstlane(tid >> 6);  // wave 0..7

        for (int i = tid; i < 4 * 64; i += 512) cLDS[i] = 0.0f;

        float bGi = 0, bGf = 0, bGg = 0, bGo = 0;
        if (tid < 256) {
            const int j = tid >> 6;
            bGi = bias[0 * E_ + e0 + j];
            bGf = bias[1 * E_ + e0 + j];
            bGg = bias[2 * E_ + e0 + j];
            bGo = bias[3 * E_ + e0 + j];
        }
        __syncthreads();

        float acc[16];
        float4 px[4];
        unsigned long long pfh[4];

        const int s_bb = tid >> 5, s_q = tid & 31;      // x-staging coords
        const int h_row = tid >> 4, h_col = (tid & 15) * 4;  // h-staging coords

        // prefetch x tile0 of t=0
        {
            const int t_eff = dir ? (T_ - 1) : 0;
            const float4* xs4 = (const float4*)(seq + (size_t)t_eff * B_ * F_);
            #pragma unroll
            for (int s = 0; s < 4; ++s) {
                int idx = tid + s * 512;
                px[s] = xs4[(idx >> 5) * 64 + (idx & 31)];
            }
        }

        for (int t = 0; t < T_; ++t) {
            const int t_eff = dir ? (T_ - 1 - t) : t;
            const float4* xs4 = (const float4*)(seq + (size_t)t_eff * B_ * F_);

            #pragma unroll
            for (int r = 0; r < 16; ++r) acc[r] = 0.0f;

            // ---- x part first (h-independent): hides barrier spread ----
            __syncthreads();                 // buf free
            #pragma unroll
            for (int s = 0; s < 4; ++s) {
                int idx = tid + s * 512, bb = idx >> 5, q = idx & 31;
                buf[(q * 4 + 0) * 65 + bb] = px[s].x;
                buf[(q * 4 + 1) * 65 + bb] = px[s].y;
                buf[(q * 4 + 2) * 65 + bb] = px[s].z;
                buf[(q * 4 + 3) * 65 + bb] = px[s].w;
            }
            __syncthreads();                 // tile ready
            #pragma unroll
            for (int s = 0; s < 4; ++s) {    // prefetch x tile1
                int idx = tid + s * 512;
                px[s] = xs4[(idx >> 5) * 64 + 32 + (idx & 31)];
            }
            {   // compute x tile0
                const int koff = g * 16;
                #pragma unroll
                for (int kk = 0; kk < 16; ++kk) {
                    float xv = buf[(g * 16 + kk) * 65 + b];
                    #pragma unroll
                    for (int r = 0; r < 16; ++r) {
                        const int grow = (r >> 2) * E_ + e0 + (r & 3);
                        acc[r] = fmaf(Wih[(size_t)grow * F_ + koff + kk], xv, acc[r]);
                    }
                }
            }
            __syncthreads();                 // buf consumed
            #pragma unroll
            for (int s = 0; s < 4; ++s) {
                int idx = tid + s * 512, bb = idx >> 5, q = idx & 31;
                buf[(q * 4 + 0) * 65 + bb] = px[s].x;
                buf[(q * 4 + 1) * 65 + bb] = px[s].y;
                buf[(q * 4 + 2) * 65 + bb] = px[s].z;
                buf[(q * 4 + 3) * 65 + bb] = px[s].w;
            }
            __syncthreads();
            {   // compute x tile1
                const int koff = 128 + g * 16;
                #pragma unroll
                for (int kk = 0; kk < 16; ++kk) {
                    float xv = buf[(g * 16 + kk) * 65 + b];
                    #pragma unroll
                    for (int r = 0; r < 16; ++r) {
                        const int grow = (r >> 2) * E_ + e0 + (r & 3);
                        acc[r] = fmaf(Wih[(size_t)grow * F_ + koff + kk], xv, acc[r]);
                    }
                }
            }

            // ---- wait until all blocks produced h_t ----
            if (t > 0 && tid < 64) {
                const unsigned long long* pp = (const unsigned long long*)slots;
                const unsigned tgt = (unsigned)t;
                bool ok;
                do {
                    unsigned long long v = aload_u64(pp + tid);
                    ok = ((unsigned)v >= tgt) && ((unsigned)(v >> 32) >= tgt);
                } while (!__all(ok));
            }
            __syncthreads();                 // orders h loads after poll

            const unsigned short* hsrc = ring + (size_t)t * (E_ * B_);
            #pragma unroll
            for (int s = 0; s < 4; ++s)      // prefetch h tile0 (normal cached)
                pfh[s] = ((const unsigned long long*)hsrc)[tid + s * 512];

            for (int ht = 0; ht < 4; ++ht) {
                __syncthreads();             // buf free
                #pragma unroll
                for (int s = 0; s < 4; ++s) {
                    int u = tid + s * 512;
                    int row = u >> 4, col = (u & 15) * 4;
                    unsigned long long v = pfh[s];
                    buf[row * 65 + col + 0] = bfbits2f((unsigned)(v & 0xffff));
                    buf[row * 65 + col + 1] = bfbits2f((unsigned)((v >> 16) & 0xffff));
                    buf[row * 65 + col + 2] = bfbits2f((unsigned)((v >> 32) & 0xffff));
                    buf[row * 65 + col + 3] = bfbits2f((unsigned)((v >> 48) & 0xffff));
                }
                __syncthreads();             // tile ready
                if (ht < 3) {
                    const unsigned long long* nsrc =
                        (const unsigned long long*)(hsrc + (ht + 1) * 8192);
                    #pragma unroll
                    for (int s = 0; s < 4; ++s) pfh[s] = nsrc[tid + s * 512];
                }
                const int koff = ht * 128 + g * 16;
                #pragma unroll
                for (int kk = 0; kk < 16; ++kk) {
                    float xv = buf[(g * 16 + kk) * 65 + b];
                    #pragma unroll
                    for (int r = 0; r < 16; ++r) {
                        const int grow = (r >> 2) * E_ + e0 + (r & 3);
                        acc[r] = fmaf(Whh[(size_t)grow * E_ + koff + kk], xv, acc[r]);
                    }
                }
            }
            // ---- reduce 8 wave-partials ----
            #pragma unroll
            for (int r = 0; r < 16; ++r) part[(g * 16 + r) * 65 + b] = acc[r];
            __syncthreads();
            {
                const int r0 = tid >> 6;
                #pragma unroll
                for (int h2 = 0; h2 < 2; ++h2) {
                    const int r = r0 + h2 * 8;
                    float sum = 0.0f;
                    #pragma unroll
                    for (int gg = 0; gg < 8; ++gg) sum += part[(gg * 16 + r) * 65 + b];
                    pre[r * 65 + b] = sum;
                }
            }
            __syncthreads();
            if (tid < 256) {
                const int bb = tid & 63, j = tid >> 6;
                float gI = pre[(0 * 4 + j) * 65 + bb] + bGi;
                float gF = pre[(1 * 4 + j) * 65 + bb] + bGf;
                float gG = pre[(2 * 4 + j) * 65 + bb] + bGg;
                float gO = pre[(3 * 4 + j) * 65 + bb] + bGo;
                float c = cLDS[j * 64 + bb];
                c = sigmoidf_(gF) * c + sigmoidf_(gI) * tanhf(gG);
                float h = sigmoidf_(gO) * tanhf(c);
                cLDS[j * 64 + bb] = c;
                astore_us(&ring[(size_t)(t + 1) * (E_ * B_) + (e0 + j) * B_ + bb], f2bf(h));
            }
            __syncthreads();                 // drain sc1 stores (vmcnt(0) @ barrier)
            if (tid == 0) astore_u32(myslot, (unsigned)(t + 1));
            // prefetch x tile0 of next step while laggards catch up
            if (t + 1 < T_) {
                const int tn = dir ? (T_ - 2 - t) : (t + 1);
                const float4* xn4 = (const float4*)(seq + (size_t)tn * B_ * F_);
                #pragma unroll
                for (int s = 0; s < 4; ++s) {
                    int idx = tid + s * 512;
                    px[s] = xn4[(idx >> 5) * 64 + (idx & 31)];
                }
            }
        }
        // join both directions
        {
            const unsigned long long* pf_ = (const unsigned long long*)slotsF;
            const unsigned long long* pb_ = (const unsigned long long*)slotsB;
            if (tid < 64) {
                bool ok;
                do {
                    unsigned long long v0 = aload_u64(pf_ + tid);
                    unsigned long long v1 = aload_u64(pb_ + tid);
                    ok = ((unsigned)v0 >= (unsigned)T_) && ((unsigned)(v0 >> 32) >= (unsigned)T_) &&
                         ((unsigned)v1 >= (unsigned)T_) && ((unsigned)(v1 >> 32) >= (unsigned)T_);
                } while (!__all(ok));
            }
            __syncthreads();
        }
    }

    // ================= xp0 = [h_f | h_b] @ dec_Wih^T + dec_b =================
    {
        const int b  = tid & 63;
        const int r4 = (tid >> 6) & 3;
        const int r  = bid * 4 + r4;                 // 0..1023
        const float* wr = dWih + (size_t)r * (2 * E_);
        float accv = db[r];
        const unsigned short* hfFin = hfR + (size_t)T_ * (E_ * B_);
        const unsigned short* hbFin = hbR + (size_t)T_ * (E_ * B_);
        for (int ch = 0; ch < 8; ++ch) {
            const unsigned short* src = (ch < 4 ? hfFin : hbFin) + (ch & 3) * 8192;
            __syncthreads();
            #pragma unroll
            for (int s = 0; s < 4; ++s) {
                int u = tid + s * 512;
                int row = u >> 4, col = (u & 15) * 4;
                unsigned long long v = ((const unsigned long long*)src)[u];
                buf[row * 65 + col + 0] = bfbits2f((unsigned)(v & 0xffff));
                buf[row * 65 + col + 1] = bfbits2f((unsigned)((v >> 16) & 0xffff));
                buf[row * 65 + col + 2] = bfbits2f((unsigned)((v >> 32) & 0xffff));
                buf[row * 65 + col + 3] = bfbits2f((unsigned)((v >> 48) & 0xffff));
            }
            __syncthreads();
            if (tid < 256) {
                const float* w = wr + ch * 128;
                #pragma unroll 8
                for (int kk = 0; kk < 128; ++kk)
                    accv = fmaf(w[kk], buf[kk * 65 + b], accv);
            }
        }
        if (tid < 256) astore_f(&xp0T[r * B_ + b], accv);
        __syncthreads();                 // drain before arrival
        if (tid == 0) astore_u32(slotsX + bid, 1u);
        if (bid >= 64) return;
        if (tid < 64) {
            const unsigned long long* pp = (const unsigned long long*)slotsX;
            bool ok;
            do {
                unsigned long long v0 = aload_u64(pp + 2 * tid);
                unsigned long long v1 = aload_u64(pp + 2 * tid + 1);
                ok = ((unsigned)v0 != 0u) && ((unsigned)(v0 >> 32) != 0u) &&
                     ((unsigned)v1 != 0u) && ((unsigned)(v1 >> 32) != 0u);
            } while (!__all(ok));
        }
        __syncthreads();
    }

    // ================= decoder: 64 blocks x 4 f-dims, 512 steps =================
    {
        const int fb0 = bid * 4;
        const int b = tid & 63;
        const int g = __builtin_amdgcn_readfirstlane(tid >> 6);

        for (int i = tid; i < 4 * 64; i += 512) cLDS[i] = 0.0f;
        #pragma unroll
        for (int s = 0; s < 2; ++s) {        // xp0 slice -> LDS (normal cached)
            int u = tid + s * 512;
            int r16 = u >> 6, bb = u & 63;
            xpLDS[r16 * 64 + bb] = xp0T[((r16 >> 2) * F_ + fb0 + (r16 & 3)) * B_ + bb];
        }
        __syncthreads();

        float acc[16];
        unsigned long long pfh[4];

        for (int t = 0; t < T_; ++t) {
            if (t > 0 && tid < 64) {
                const unsigned tgt = (unsigned)t;
                bool ok;
                do {
                    unsigned v = aload_u32(slotsD + tid);
                    ok = (v >= tgt);
                } while (!__all(ok));
            }
            __syncthreads();

            const unsigned short* hsrc = hdR + (size_t)t * (F_ * B_);
            #pragma unroll
            for (int s = 0; s < 4; ++s)
                pfh[s] = ((const unsigned long long*)hsrc)[tid + s * 512];

            #pragma unroll
            for (int r = 0; r < 16; ++r) acc[r] = 0.0f;

            for (int kt = 0; kt < 2; ++kt) {
                __syncthreads();
                #pragma unroll
                for (int s = 0; s < 4; ++s) {
                    int u = tid + s * 512;
                    int row = u >> 4, col = (u & 15) * 4;
                    unsigned long long v = pfh[s];
                    buf[row * 65 + col + 0] = bfbits2f((unsigned)(v & 0xffff));
                    buf[row * 65 + col + 1] = bfbits2f((unsigned)((v >> 16) & 0xffff));
                    buf[row * 65 + col + 2] = bfbits2f((unsigned)((v >> 32) & 0xffff));
                    buf[row * 65 + col + 3] = bfbits2f((unsigned)((v >> 48) & 0xffff));
                }
                __syncthreads();
                if (kt == 0) {
                    const unsigned long long* nsrc =
                        (const unsigned long long*)(hsrc + 8192);
                    #pragma unroll
                    for (int s = 0; s < 4; ++s) pfh[s] = nsrc[tid + s * 512];
                }
                const int koff = kt * 128 + g * 16;
                #pragma unroll
                for (int kk = 0; kk < 16; ++kk) {
                    float xv = buf[(g * 16 + kk) * 65 + b];
                    #pragma unroll
                    for (int r = 0; r < 16; ++r) {
                        const int grow = (r >> 2) * F_ + fb0 + (r & 3);
                        acc[r] = fmaf(dWhh[(size_t)grow * F_ + koff + kk], xv, acc[r]);
                    }
                }
            }
            #pragma unroll
            for (int r = 0; r < 16; ++r) part[(g * 16 + r) * 65 + b] = acc[r];
            __syncthreads();
            {
                const int r0 = tid >> 6;
                #pragma unroll
                for (int h2 = 0; h2 < 2; ++h2) {
                    const int r = r0 + h2 * 8;
                    float sum = 0.0f;
                    #pragma unroll
                    for (int gg = 0; gg < 8; ++gg) sum += part[(gg * 16 + r) * 65 + b];
                    pre[r * 65 + b] = sum;
                }
            }
            __syncthreads();
            if (tid < 256) {
                const int bb = tid & 63, j = tid >> 6;
                float gI = pre[(0 * 4 + j) * 65 + bb] + xpLDS[(0 * 4 + j) * 64 + bb];
                float gF = pre[(1 * 4 + j) * 65 + bb] + xpLDS[(1 * 4 + j) * 64 + bb];
                float gG = pre[(2 * 4 + j) * 65 + bb] + xpLDS[(2 * 4 + j) * 64 + bb];
                float gO = pre[(3 * 4 + j) * 65 + bb] + xpLDS[(3 * 4 + j) * 64 + bb];
                float c = cLDS[j * 64 + bb];
                c = sigmoidf_(gF) * c + sigmoidf_(gI) * tanhf(gG);
                float h = sigmoidf_(gO) * tanhf(c);
                cLDS[j * 64 + bb] = c;
                astore_us(&hdR[(size_t)(t + 1) * (F_ * B_) + (fb0 + j) * B_ + bb], f2bf(h));
                out[(size_t)t * B_ * F_ + (size_t)bb * F_ + fb0 + j] = h;
            }
            __syncthreads();                 // drain
            if (tid == 0) astore_u32(slotsD + bid, (unsigned)(t + 1));
        }
    }
}

extern "C" void kernel_launch(void* const* d_in, const int* in_sizes, int n_in,
                              void* d_out, int out_size, void* d_ws, size_t ws_size,
                              hipStream_t stream) {
    const float* seq  = (const float*)d_in[0];
    const float* WihF = (const float*)d_in[1];
    const float* WhhF = (const float*)d_in[2];
    const float* bF   = (const float*)d_in[3];
    const float* WihB = (const float*)d_in[4];
    const float* WhhB = (const float*)d_in[5];
    const float* bB   = (const float*)d_in[6];
    const float* dWih = (const float*)d_in[7];
    const float* dWhh = (const float*)d_in[8];
    const float* db   = (const float*)d_in[9];
    float* out = (float*)d_out;
    char* ws   = (char*)d_ws;

    void* args[] = { &seq, &WihF, &WhhF, &bF, &WihB, &WhhB, &bB,
                     &dWih, &dWhh, &db, &out, &ws };
    hipLaunchCooperativeKernel((void*)autoenc_kernel, dim3(256), dim3(512),
                               args, 0, stream);
}

// Round 5
// 6659.536 us; speedup vs baseline: 6.6216x; 1.6986x over previous
//
#include <hip/hip_runtime.h>
#include <hip/hip_cooperative_groups.h>

namespace cg = cooperative_groups;

#define T_  512
#define B_  64
#define F_  256
#define E_  512
#define AGENT __HIP_MEMORY_SCOPE_AGENT

typedef __bf16 bf16x8 __attribute__((ext_vector_type(8)));
typedef float  f32x4  __attribute__((ext_vector_type(4)));

// ---- ws layout (bytes). Write-once rings, B-MAJOR: ring[t][b][dim] bf16.
// Producers sc1-store (bypass L2 -> L3); consumers use normal cached loads
// (lines never cached pre-write => no staleness; per-XCD L2 serves re-reads).
#define OFF_HF   0ull                    // [T+1][B][E] bf16 = 33,619,968
#define OFF_HB   33619968ull             // [T+1][B][E] bf16
#define OFF_HD   67239936ull             // [T+1][B][F] bf16 = 16,809,984
#define OFF_XP   84049920ull             // [4F][B] f32 = 262,144
#define OFF_SL   84312064ull             // slots: F64,B64,X128,D64 = 320 u32

// ---- LDS arena (bytes); weights live here for the whole kernel ----
#define L_WHH_H 0        // ushort[32][520]
#define L_WHH_L 33280
#define L_WIH_H 66560    // ushort[32][264]
#define L_WIH_L 83456
#define L_DWH_H 100352   // ushort[16][264]
#define L_DWH_L 108800
#define L_PRE   117248   // float[32][68]  (decoder: [2][16][68])
#define L_HPACK 125952   // ushort[64][8]
#define L_TOTAL 126976
#define LDK_H 520        // whh lds row stride (ushorts): 260 words %32 = 4 -> conflict-free b128
#define LDK_X 264        // wih/dwhh stride: 132 words %32 = 4
#define LDP   68         // pre row stride (floats)

__device__ __forceinline__ float sigmoidf_(float x) {
    return 1.0f / (1.0f + __expf(-x));
}
__device__ __forceinline__ unsigned short f2bf(float f) {   // RNE
    unsigned u = __float_as_uint(f);
    u += 0x7fffu + ((u >> 16) & 1u);
    return (unsigned short)(u >> 16);
}
__device__ __forceinline__ float bfbits2f(unsigned us) {
    return __uint_as_float(us << 16);
}
__device__ __forceinline__ void astore_u32(unsigned* p, unsigned v) {
    __hip_atomic_store(p, v, __ATOMIC_RELAXED, AGENT);
}
__device__ __forceinline__ unsigned aload_u32(const unsigned* p) {
    return __hip_atomic_load(p, __ATOMIC_RELAXED, AGENT);
}
__device__ __forceinline__ void astore_u64(unsigned long long* p, unsigned long long v) {
    __hip_atomic_store(p, v, __ATOMIC_RELAXED, AGENT);
}
__device__ __forceinline__ void astore_f(float* p, float v) {
    __hip_atomic_store(p, v, __ATOMIC_RELAXED, AGENT);
}

__global__ __launch_bounds__(512, 1)
void autoenc_kernel(const float* __restrict__ seq,
                    const float* __restrict__ WihF, const float* __restrict__ WhhF, const float* __restrict__ bF,
                    const float* __restrict__ WihB, const float* __restrict__ WhhB, const float* __restrict__ bB,
                    const float* __restrict__ dWih, const float* __restrict__ dWhh, const float* __restrict__ db,
                    float* __restrict__ out, char* __restrict__ ws)
{
    cg::grid_group grid = cg::this_grid();
    const int tid = threadIdx.x;
    const int bid = blockIdx.x;

    unsigned short* hfR = (unsigned short*)(ws + OFF_HF);
    unsigned short* hbR = (unsigned short*)(ws + OFF_HB);
    unsigned short* hdR = (unsigned short*)(ws + OFF_HD);
    float* xp0T = (float*)(ws + OFF_XP);
    unsigned* slotsF = (unsigned*)(ws + OFF_SL);   // [64]
    unsigned* slotsB = slotsF + 64;                // [64]
    unsigned* slotsX = slotsB + 64;                // [128]
    unsigned* slotsD = slotsX + 128;               // [64]

    __shared__ __align__(16) char arena[L_TOTAL];
    unsigned short* whhH = (unsigned short*)(arena + L_WHH_H);
    unsigned short* whhL = (unsigned short*)(arena + L_WHH_L);
    unsigned short* wihH = (unsigned short*)(arena + L_WIH_H);
    unsigned short* wihL = (unsigned short*)(arena + L_WIH_L);
    unsigned short* dwhH = (unsigned short*)(arena + L_DWH_H);
    unsigned short* dwhL = (unsigned short*)(arena + L_DWH_L);
    float* pre = (float*)(arena + L_PRE);
    unsigned short* hpack = (unsigned short*)(arena + L_HPACK);

    const int dir = bid >> 6;          // 0 fwd (blocks 0..63), 1 bwd (64..127)
    const int blk = bid & 63;
    const int e0  = blk * 8;           // encoder block owns h dims [e0, e0+8)
    const float* Wih  = dir ? WihB : WihF;
    const float* Whh  = dir ? WhhB : WhhF;
    const float* bias = dir ? bB   : bF;
    unsigned short* ring = dir ? hbR : hfR;
    unsigned* slots  = dir ? slotsB : slotsF;
    unsigned* myslot = slots + blk;

    // ---- init: zero ring[0] slabs + slots (sc1 only) ----
    {
        unsigned* hf0 = (unsigned*)hfR;
        unsigned* hb0 = (unsigned*)hbR;
        unsigned* hd0 = (unsigned*)hdR;
        for (int i = bid * 512 + tid; i < 16384; i += 128 * 512) { astore_u32(hf0 + i, 0u); astore_u32(hb0 + i, 0u); }
        for (int i = bid * 512 + tid; i < 8192;  i += 128 * 512) astore_u32(hd0 + i, 0u);
        if (bid == 0 && tid < 320) astore_u32(slotsF + tid, 0u);
    }

    // ---- one-time weight conversion fp32 -> bf16 hi/lo in LDS ----
    for (int idx = tid; idx < 32 * 512; idx += 512) {        // Whh 32 rows x 512
        int r = idx >> 9, k = idx & 511;
        int grow = (r >> 3) * E_ + e0 + (r & 7);
        float w = Whh[(size_t)grow * E_ + k];
        __bf16 h16 = (__bf16)w;
        __bf16 l16 = (__bf16)(w - (float)h16);
        whhH[r * LDK_H + k] = __builtin_bit_cast(unsigned short, h16);
        whhL[r * LDK_H + k] = __builtin_bit_cast(unsigned short, l16);
    }
    for (int idx = tid; idx < 32 * 256; idx += 512) {        // Wih 32 rows x 256
        int r = idx >> 8, k = idx & 255;
        int grow = (r >> 3) * E_ + e0 + (r & 7);
        float w = Wih[(size_t)grow * F_ + k];
        __bf16 h16 = (__bf16)w;
        __bf16 l16 = (__bf16)(w - (float)h16);
        wihH[r * LDK_X + k] = __builtin_bit_cast(unsigned short, h16);
        wihL[r * LDK_X + k] = __builtin_bit_cast(unsigned short, l16);
    }
    if (bid < 64) {                                          // dec Whh 16 rows x 256
        const int fb0 = bid * 4;
        for (int idx = tid; idx < 16 * 256; idx += 512) {
            int r = idx >> 8, k = idx & 255;
            int grow = (r >> 2) * F_ + fb0 + (r & 3);
            float w = dWhh[(size_t)grow * F_ + k];
            __bf16 h16 = (__bf16)w;
            __bf16 l16 = (__bf16)(w - (float)h16);
            dwhH[r * LDK_X + k] = __builtin_bit_cast(unsigned short, h16);
            dwhL[r * LDK_X + k] = __builtin_bit_cast(unsigned short, l16);
        }
    }
    __syncthreads();
    grid.sync();   // one-time fence: L2s invalidated (post-poison), ring[0]/slots visible

    const int w    = tid >> 6;        // wave 0..7
    const int lane = tid & 63;
    const int col  = lane & 15;       // A: m-index / B: n-index / D: col
    const int quad = lane >> 4;

    // ================= encoder: bidirectional LSTM (MFMA) =================
    {
        const int mt = w & 1, nt = w >> 1;       // C-tile: rows [mt*16,+16) x b [nt*16,+16)
        const int bcol = nt * 16 + col;          // batch column for B-frags
        const unsigned short* aHh = whhH + (mt * 16 + col) * LDK_H + quad * 8;
        const unsigned short* aHl = whhL + (mt * 16 + col) * LDK_H + quad * 8;
        const unsigned short* aXh = wihH + (mt * 16 + col) * LDK_X + quad * 8;
        const unsigned short* aXl = wihL + (mt * 16 + col) * LDK_X + quad * 8;

        // epilogue thread (j,b) state in registers
        const int ej = tid & 7, eb = tid >> 3;
        const float bGi = bias[0 * E_ + e0 + ej];
        const float bGf = bias[1 * E_ + e0 + ej];
        const float bGg = bias[2 * E_ + e0 + ej];
        const float bGo = bias[3 * E_ + e0 + ej];
        float creg = 0.0f;

        for (int t = 0; t < T_; ++t) {
            const int t_eff = dir ? (T_ - 1 - t) : t;
            f32x4 acc = {0.f, 0.f, 0.f, 0.f};

            // ---- x-part first (h-independent; hides barrier spread) ----
            {
                const float* xrow = seq + (size_t)t_eff * B_ * F_ + bcol * F_ + quad * 8;
                #pragma unroll
                for (int kt = 0; kt < 8; ++kt) {
                    float4 v0 = *(const float4*)(xrow + kt * 32);
                    float4 v1 = *(const float4*)(xrow + kt * 32 + 4);
                    float vv[8] = {v0.x, v0.y, v0.z, v0.w, v1.x, v1.y, v1.z, v1.w};
                    bf16x8 xh, xl;
                    #pragma unroll
                    for (int j2 = 0; j2 < 8; ++j2) {
                        __bf16 hv = (__bf16)vv[j2];
                        xh[j2] = hv;
                        xl[j2] = (__bf16)(vv[j2] - (float)hv);
                    }
                    bf16x8 ah = *(const bf16x8*)(aXh + kt * 32);
                    bf16x8 al = *(const bf16x8*)(aXl + kt * 32);
                    acc = __builtin_amdgcn_mfma_f32_16x16x32_bf16(ah, xh, acc, 0, 0, 0);
                    acc = __builtin_amdgcn_mfma_f32_16x16x32_bf16(al, xh, acc, 0, 0, 0);
                    acc = __builtin_amdgcn_mfma_f32_16x16x32_bf16(ah, xl, acc, 0, 0, 0);
                }
            }

            // ---- wait for h_t ----
            if (t > 0 && tid < 64) {
                const unsigned tgt = (unsigned)t;
                bool ok;
                do { ok = (aload_u32(slots + tid) >= tgt); } while (!__all(ok));
            }
            __syncthreads();

            // ---- h-part: B-frags straight from b-major ring (cached loads) ----
            {
                const unsigned short* hrow = ring + (size_t)t * (B_ * E_) + bcol * E_ + quad * 8;
                #pragma unroll
                for (int kt = 0; kt < 16; ++kt) {
                    uint4 q = *(const uint4*)(hrow + kt * 32);
                    bf16x8 hb = __builtin_bit_cast(bf16x8, q);
                    bf16x8 ah = *(const bf16x8*)(aHh + kt * 32);
                    bf16x8 al = *(const bf16x8*)(aHl + kt * 32);
                    acc = __builtin_amdgcn_mfma_f32_16x16x32_bf16(ah, hb, acc, 0, 0, 0);
                    acc = __builtin_amdgcn_mfma_f32_16x16x32_bf16(al, hb, acc, 0, 0, 0);
                }
            }
            // ---- dump C-frags: D[row=quad*4+rg][col] ----
            #pragma unroll
            for (int rg = 0; rg < 4; ++rg)
                pre[(mt * 16 + quad * 4 + rg) * LDP + nt * 16 + col] = acc[rg];
            __syncthreads();

            // ---- epilogue: thread owns (ej, eb) ----
            {
                float gI = pre[(0 * 8 + ej) * LDP + eb] + bGi;
                float gF = pre[(1 * 8 + ej) * LDP + eb] + bGf;
                float gG = pre[(2 * 8 + ej) * LDP + eb] + bGg;
                float gO = pre[(3 * 8 + ej) * LDP + eb] + bGo;
                creg = sigmoidf_(gF) * creg + sigmoidf_(gI) * tanhf(gG);
                float h = sigmoidf_(gO) * tanhf(creg);
                hpack[eb * 8 + ej] = f2bf(h);
            }
            __syncthreads();
            if (tid < 64) {      // 16 B of h per batch row, sc1 to ring[t+1]
                unsigned long long* dst = (unsigned long long*)
                    (ring + (size_t)(t + 1) * (B_ * E_) + tid * E_ + e0);
                const unsigned long long* src = (const unsigned long long*)(hpack + tid * 8);
                astore_u64(dst + 0, src[0]);
                astore_u64(dst + 1, src[1]);
            }
            __syncthreads();     // drains wave0's sc1 stores before signal
            if (tid == 0) astore_u32(myslot, (unsigned)(t + 1));
        }
        // join both directions
        if (tid < 64) {
            bool ok;
            do {
                ok = (aload_u32(slotsF + tid) >= (unsigned)T_) &&
                     (aload_u32(slotsB + tid) >= (unsigned)T_);
            } while (!__all(ok));
        }
        __syncthreads();
    }

    // ================= xp0 = [h_f | h_b] @ dec_Wih^T + dec_b =================
    {
        const int r8 = tid >> 6, xb = tid & 63;
        const int r = bid * 8 + r8;                       // 0..1023
        const float* wr = dWih + (size_t)r * (2 * E_);    // wave-uniform row
        float accv = db[r];
        const unsigned short* hf_ = hfR + (size_t)T_ * (B_ * E_) + xb * E_;
        const unsigned short* hb_ = hbR + (size_t)T_ * (B_ * E_) + xb * E_;
        for (int kc = 0; kc < 128; ++kc) {
            unsigned long long v = *(const unsigned long long*)(hf_ + kc * 4);
            accv = fmaf(wr[kc * 4 + 0], bfbits2f((unsigned)(v & 0xffff)), accv);
            accv = fmaf(wr[kc * 4 + 1], bfbits2f((unsigned)((v >> 16) & 0xffff)), accv);
            accv = fmaf(wr[kc * 4 + 2], bfbits2f((unsigned)((v >> 32) & 0xffff)), accv);
            accv = fmaf(wr[kc * 4 + 3], bfbits2f((unsigned)((v >> 48) & 0xffff)), accv);
        }
        for (int kc = 0; kc < 128; ++kc) {
            unsigned long long v = *(const unsigned long long*)(hb_ + kc * 4);
            accv = fmaf(wr[E_ + kc * 4 + 0], bfbits2f((unsigned)(v & 0xffff)), accv);
            accv = fmaf(wr[E_ + kc * 4 + 1], bfbits2f((unsigned)((v >> 16) & 0xffff)), accv);
            accv = fmaf(wr[E_ + kc * 4 + 2], bfbits2f((unsigned)((v >> 32) & 0xffff)), accv);
            accv = fmaf(wr[E_ + kc * 4 + 3], bfbits2f((unsigned)((v >> 48) & 0xffff)), accv);
        }
        astore_f(&xp0T[r * B_ + xb], accv);
        __syncthreads();         // drain all waves' xp0 stores
        if (tid == 0) astore_u32(slotsX + bid, 1u);
        if (bid >= 64) return;
        if (tid < 64) {
            bool ok;
            do {
                ok = (aload_u32(slotsX + tid) != 0u) && (aload_u32(slotsX + 64 + tid) != 0u);
            } while (!__all(ok));
        }
        __syncthreads();
    }

    // ================= decoder: 64 blocks x 4 f-dims (MFMA) =================
    {
        const int fb0 = bid * 4;
        const int ntD = w & 3, kh = w >> 2;      // N-tile, K-half per wave
        const int bcolD = ntD * 16 + col;
        const unsigned short* aDh = dwhH + col * LDK_X + kh * 128 + quad * 8;
        const unsigned short* aDl = dwhL + col * LDK_X + kh * 128 + quad * 8;

        const int ej = tid & 3, eb = tid >> 2;   // epilogue (j,b) for tid<256
        float xg0 = 0, xg1 = 0, xg2 = 0, xg3 = 0;
        if (tid < 256) {
            xg0 = xp0T[(0 * F_ + fb0 + ej) * B_ + eb];
            xg1 = xp0T[(1 * F_ + fb0 + ej) * B_ + eb];
            xg2 = xp0T[(2 * F_ + fb0 + ej) * B_ + eb];
            xg3 = xp0T[(3 * F_ + fb0 + ej) * B_ + eb];
        }
        float creg = 0.0f;

        for (int t = 0; t < T_; ++t) {
            if (t > 0 && tid < 64) {
                const unsigned tgt = (unsigned)t;
                bool ok;
                do { ok = (aload_u32(slotsD + tid) >= tgt); } while (!__all(ok));
            }
            __syncthreads();

            f32x4 acc = {0.f, 0.f, 0.f, 0.f};
            const unsigned short* hrow = hdR + (size_t)t * (B_ * F_) + bcolD * F_ + kh * 128 + quad * 8;
            #pragma unroll
            for (int kt = 0; kt < 4; ++kt) {
                uint4 q = *(const uint4*)(hrow + kt * 32);
                bf16x8 hb = __builtin_bit_cast(bf16x8, q);
                bf16x8 ah = *(const bf16x8*)(aDh + kt * 32);
                bf16x8 al = *(const bf16x8*)(aDl + kt * 32);
                acc = __builtin_amdgcn_mfma_f32_16x16x32_bf16(ah, hb, acc, 0, 0, 0);
                acc = __builtin_amdgcn_mfma_f32_16x16x32_bf16(al, hb, acc, 0, 0, 0);
            }
            #pragma unroll
            for (int rg = 0; rg < 4; ++rg)
                pre[kh * (16 * LDP) + (quad * 4 + rg) * LDP + ntD * 16 + col] = acc[rg];
            __syncthreads();

            if (tid < 256) {
                float gI = pre[(0 * 4 + ej) * LDP + eb] + pre[16 * LDP + (0 * 4 + ej) * LDP + eb] + xg0;
                float gF = pre[(1 * 4 + ej) * LDP + eb] + pre[16 * LDP + (1 * 4 + ej) * LDP + eb] + xg1;
                float gG = pre[(2 * 4 + ej) * LDP + eb] + pre[16 * LDP + (2 * 4 + ej) * LDP + eb] + xg2;
                float gO = pre[(3 * 4 + ej) * LDP + eb] + pre[16 * LDP + (3 * 4 + ej) * LDP + eb] + xg3;
                creg = sigmoidf_(gF) * creg + sigmoidf_(gI) * tanhf(gG);
                float h = sigmoidf_(gO) * tanhf(creg);
                hpack[eb * 4 + ej] = f2bf(h);
                out[(size_t)t * B_ * F_ + (size_t)eb * F_ + fb0 + ej] = h;
            }
            __syncthreads();
            if (tid < 64) {
                unsigned long long* dst = (unsigned long long*)
                    (hdR + (size_t)(t + 1) * (B_ * F_) + tid * F_ + fb0);
                astore_u64(dst, *(const unsigned long long*)(hpack + tid * 4));
            }
            __syncthreads();     // drain before signal
            if (tid == 0) astore_u32(slotsD + bid, (unsigned)(t + 1));
        }
    }
}

extern "C" void kernel_launch(void* const* d_in, const int* in_sizes, int n_in,
                              void* d_out, int out_size, void* d_ws, size_t ws_size,
                              hipStream_t stream) {
    const float* seq  = (const float*)d_in[0];
    const float* WihF = (const float*)d_in[1];
    const float* WhhF = (const float*)d_in[2];
    const float* bF   = (const float*)d_in[3];
    const float* WihB = (const float*)d_in[4];
    const float* WhhB = (const float*)d_in[5];
    const float* bB   = (const float*)d_in[6];
    const float* dWih = (const float*)d_in[7];
    const float* dWhh = (const float*)d_in[8];
    const float* db   = (const float*)d_in[9];
    float* out = (float*)d_out;
    char* ws   = (char*)d_ws;

    void* args[] = { &seq, &WihF, &WhhF, &bF, &WihB, &WhhB, &bB,
                     &dWih, &dWhh, &db, &out, &ws };
    hipLaunchCooperativeKernel((void*)autoenc_kernel, dim3(128), dim3(512),
                               args, 0, stream);
}